// Round 6
// baseline (461.302 us; speedup 1.0000x reference)
//
#include <hip/hip_runtime.h>

#define B_ROWS 32768
#define T_BINS 1024

typedef __attribute__((ext_vector_type(8))) _Float16 half8;
typedef __attribute__((ext_vector_type(4))) float floatx4;

__device__ __forceinline__ unsigned long long pack_max(float v, int col) {
    unsigned x = __float_as_uint(v);
    x = (x & 0x80000000u) ? ~x : (x | 0x80000000u);   // monotone float->uint
    return ((unsigned long long)x << 32) | (unsigned)(~col);  // ties -> smaller col
}

__device__ __forceinline__ void async16h(const _Float16* g, _Float16* l) {
    __builtin_amdgcn_global_load_lds(
        (const __attribute__((address_space(1))) unsigned int*)g,
        (__attribute__((address_space(3))) unsigned int*)l,
        16, 0, 0);
}

// ---------------- convert fp32 -> f16 (RNE), used for W only ----------------
__global__ __launch_bounds__(256) void tof16_kernel(
    const float* __restrict__ src, _Float16* __restrict__ dst, int n4)
{
    int idx = blockIdx.x * 256 + threadIdx.x;
    if (idx >= n4) return;
    float4 x = ((const float4*)src)[idx];
    union { _Float16 h[4]; ushort4 u; } cv;
    cv.h[0] = (_Float16)x.x;
    cv.h[1] = (_Float16)x.y;
    cv.h[2] = (_Float16)x.z;
    cv.h[3] = (_Float16)x.w;
    ((ushort4*)dst)[idx] = cv.u;
}

// ---------------- R10: GEMM+argmax, 128 rows x 512 cols per block ----------------
// Invariant from R4/R7/R8/R9: staging throughput ~38 GB/s/CU at c>=2 blocks/CU;
// collapses ~3x at c=1 (R9). So: minimize staged bytes/output s.t. c>=2.
// bytes/out = 2048*(1/W_c + 1/R), LDS = 256*(R+W_c) <= 80KB. Feasible optimum with
// clean divisibility: R=128, W_c=128, C=512 -> 32 B/out (R8: 38), LDS 64KB, grid 512,
// c=2. Structure = R8's proven slot (outer col-stage x4, inner k x16 of BK=64, dbuf,
// async W, reg-staged A, plain __syncthreads). Staged/block: A 4x256KB + W 1MB = 2MB
// (R8: 2.5MB). Col-split -> per-row argmax via atomicMax rec + finscan (R9-verified).
__global__ __launch_bounds__(256, 2) void gemm_argmax_f16(
    const float* __restrict__ A, const _Float16* __restrict__ Wh,
    const float* __restrict__ bias, unsigned long long* __restrict__ rec)
{
    __shared__ _Float16 sA[2][128 * 64];   // 32 KB
    __shared__ _Float16 sW[2][128 * 64];   // 32 KB

    const int tid  = threadIdx.x;          // 0..255
    const int lane = tid & 63;
    const int w    = tid >> 6;             // wave 0..3 (32-col group within stage)
    const int slab = blockIdx.x >> 1;      // 0..255 (128-row slab)
    const int ch   = blockIdx.x & 1;       // 0..1   (512-col half)

    // ---- A staging: row=tid>>1, part=tid&1 covers phys slots part*4..+3 (of 8);
    //      phys slot ps holds source chunk ps^x8(row), x8(r)=(r^(r>>3))&7 (R9-verified)
    const int arow = tid >> 1;             // 0..127
    const int part = tid & 1;
    const int x8a  = (arow ^ (arow >> 3)) & 7;
    const float* Abase = A + (size_t)(slab * 128 + arow) * T_BINS;

    // ---- W staging: 4 asyncs/wave; async r: lane l -> local col w*32+r*8+(l>>3),
    //      phys slot l&7; source k-chunk = (l&7) ^ x8(col_local)  (R9-verified)
    const int l3  = lane >> 3;
    const int wsl = lane & 7;

    // ---- fragment reads ----
    const int l15 = lane & 15;
    const int hi  = lane >> 4;

    float run_best[8][4];
    int   run_col[8][4];
#pragma unroll
    for (int i = 0; i < 8; ++i)
#pragma unroll
        for (int r = 0; r < 4; ++r) { run_best[i][r] = -3.4e38f; run_col[i][r] = 0; }

    // ---- prologue: stage A(k=0) + W(stage0,k=0) into buf 0 ----
#pragma unroll
    for (int s = 0; s < 4; ++s) {
        int ps = part * 4 + s;
        int sc = ps ^ x8a;
        float4 f0 = *(const float4*)(Abase + sc * 8);
        float4 f1 = *(const float4*)(Abase + sc * 8 + 4);
        half8 hv;
        hv[0] = (_Float16)f0.x; hv[1] = (_Float16)f0.y; hv[2] = (_Float16)f0.z; hv[3] = (_Float16)f0.w;
        hv[4] = (_Float16)f1.x; hv[5] = (_Float16)f1.y; hv[6] = (_Float16)f1.z; hv[7] = (_Float16)f1.w;
        *(half8*)&sA[0][arow * 64 + ps * 8] = hv;
    }
#pragma unroll
    for (int r = 0; r < 4; ++r) {
        int cl = w * 32 + r * 8 + l3;                    // local col 0..127
        int sk = wsl ^ ((cl ^ (cl >> 3)) & 7);
        async16h(Wh + (size_t)(ch * 512 + cl) * T_BINS + sk * 8,
                 &sW[0][(w * 32 + r * 8) * 64]);
    }
    __syncthreads();

    // ---- main loop: 4 col-stages x 16 k-steps (BK=64), both LDS dbuf'd per slot ----
    for (int bxs = 0; bxs < 4; ++bxs) {
        const int colstage = ch * 512 + bxs * 128 + w * 32 + l15;
        float bj[2];
        bj[0] = bias[colstage];
        bj[1] = bias[colstage + 16];

        floatx4 acc[8][2];
#pragma unroll
        for (int i = 0; i < 8; ++i)
#pragma unroll
            for (int j = 0; j < 2; ++j) acc[i][j] = (floatx4){0.f, 0.f, 0.f, 0.f};

        for (int t = 0; t < 16; ++t) {
            const int n    = bxs * 16 + t;
            const int cur  = n & 1;
            const int nxt  = cur ^ 1;
            const int n1   = (n + 1) & 63;               // wrap at end harmless
            const int bxsn = n1 >> 4;
            const int kn   = (n1 & 15) * 64;

            // 1. A global loads for the next slot (regs; consumed after compute)
            float4 qa0[4], qa1[4];
#pragma unroll
            for (int s = 0; s < 4; ++s) {
                int sc = (part * 4 + s) ^ x8a;
                qa0[s] = *(const float4*)(Abase + kn + sc * 8);
                qa1[s] = *(const float4*)(Abase + kn + sc * 8 + 4);
            }

            // 2. W asyncs for the next slot into the other buffer
#pragma unroll
            for (int r = 0; r < 4; ++r) {
                int cl = w * 32 + r * 8 + l3;
                int sk = wsl ^ ((cl ^ (cl >> 3)) & 7);
                async16h(Wh + (size_t)(ch * 512 + bxsn * 128 + cl) * T_BINS + kn + sk * 8,
                         &sW[nxt][(w * 32 + r * 8) * 64]);
            }

            // 3. compute on current buffers: 2 k-subtiles x (8i x 2j)
#pragma unroll
            for (int g = 0; g < 2; ++g) {
                half8 ah[8], whf[2];
#pragma unroll
                for (int i = 0; i < 8; ++i) {
                    int rl = i * 16 + l15;
                    int xa = (rl ^ (rl >> 3)) & 7;
                    ah[i] = *(const half8*)&sA[cur][rl * 64 + (((g * 4 + hi) ^ xa) * 8)];
                }
#pragma unroll
                for (int j = 0; j < 2; ++j) {
                    int cl = w * 32 + j * 16 + l15;
                    int xw = (cl ^ (cl >> 3)) & 7;
                    whf[j] = *(const half8*)&sW[cur][cl * 64 + (((g * 4 + hi) ^ xw) * 8)];
                }
#pragma unroll
                for (int i = 0; i < 8; ++i)
#pragma unroll
                    for (int j = 0; j < 2; ++j)
                        acc[i][j] = __builtin_amdgcn_mfma_f32_16x16x32_f16(
                            ah[i], whf[j], acc[i][j], 0, 0, 0);
            }

            // 4. write A regs for next slot into the other buffer (swizzled slots)
#pragma unroll
            for (int s = 0; s < 4; ++s) {
                half8 hv;
                hv[0] = (_Float16)qa0[s].x; hv[1] = (_Float16)qa0[s].y;
                hv[2] = (_Float16)qa0[s].z; hv[3] = (_Float16)qa0[s].w;
                hv[4] = (_Float16)qa1[s].x; hv[5] = (_Float16)qa1[s].y;
                hv[6] = (_Float16)qa1[s].z; hv[7] = (_Float16)qa1[s].w;
                *(half8*)&sA[nxt][arow * 64 + (part * 4 + s) * 8] = hv;
            }

            // 5. single barrier per slot (drains asyncs + ds_writes, guards swap)
            __syncthreads();
        }

        // fold this stage's acc into the running argmax (cols strictly increase)
#pragma unroll
        for (int i = 0; i < 8; ++i)
#pragma unroll
            for (int r = 0; r < 4; ++r)
#pragma unroll
                for (int j = 0; j < 2; ++j) {
                    float v = acc[i][j][r] + bj[j];
                    if (v > run_best[i][r]) { run_best[i][r] = v; run_col[i][r] = colstage + j * 16; }
                }
    }

    // ---- epilogue: per-row argmax over this block's 512 cols ----
    // cand overlaid on dead sA (slot-63 writes went to sA[0] too, but nothing reads
    // them; final barrier above drained all LDS traffic)
    unsigned long long (*cand)[128] = reinterpret_cast<unsigned long long (*)[128]>(&sA[0][0]);

#pragma unroll
    for (int i = 0; i < 8; ++i)
#pragma unroll
        for (int r = 0; r < 4; ++r) {
            float best = run_best[i][r];
            int   bc   = run_col[i][r];
#pragma unroll
            for (int off = 8; off >= 1; off >>= 1) {
                float ov = __shfl_xor(best, off, 64);
                int   oc = __shfl_xor(bc, off, 64);
                if (ov > best || (ov == best && oc < bc)) { best = ov; bc = oc; }
            }
            if (l15 == 0)
                cand[w][i * 16 + hi * 4 + r] = pack_max(best, bc);
        }
    __syncthreads();

    if (tid < 128) {
        unsigned long long m01 = cand[0][tid] > cand[1][tid] ? cand[0][tid] : cand[1][tid];
        unsigned long long m23 = cand[2][tid] > cand[3][tid] ? cand[2][tid] : cand[3][tid];
        unsigned long long mm  = m01 > m23 ? m01 : m23;
        atomicMax(&rec[slab * 128 + tid], mm);
    }
}

// ---------------- finalize (rec -> trunc,loss) + survival scan, fused (R9-verified) ----
__global__ __launch_bounds__(256) void finscan_kernel(
    const float* __restrict__ A, const unsigned long long* __restrict__ rec,
    const float* __restrict__ labels, float* __restrict__ out_trunc,
    float* __restrict__ out_S, float* __restrict__ loss_acc)
{
    __shared__ float trunc_s[64];
    const int tid  = threadIdx.x;
    const int lane = tid & 63;
    const int wc   = tid >> 6;
    const int by   = blockIdx.x;   // 64-row slab 0..511

    if (tid < 64) {
        int rowG = by * 64 + tid;
        unsigned col = ~(unsigned)(rec[rowG] & 0xFFFFFFFFull);
        float p = (float)col;
        out_trunc[rowG] = p;
        trunc_s[tid] = p;
        float d = p - labels[rowG];
        float term = d * d * (1.0f / (float)B_ROWS);
#pragma unroll
        for (int off = 32; off >= 1; off >>= 1)
            term += __shfl_down(term, off, 64);
        if (tid == 0) atomicAdd(loss_acc, term);
    }
    __syncthreads();

    for (int rr = 0; rr < 16; ++rr) {
        int row  = wc * 16 + rr;
        int rowG = by * 64 + row;
        const float* Hrow = A + (size_t)rowG * T_BINS + lane * 16;
        float4 h0 = *(const float4*)(Hrow + 0);
        float4 h1 = *(const float4*)(Hrow + 4);
        float4 h2 = *(const float4*)(Hrow + 8);
        float4 h3 = *(const float4*)(Hrow + 12);
        float hv[16] = {h0.x, h0.y, h0.z, h0.w, h1.x, h1.y, h1.z, h1.w,
                        h2.x, h2.y, h2.z, h2.w, h3.x, h3.y, h3.z, h3.w};
        float vprod[16];
        float run = 1.f;
#pragma unroll
        for (int j = 0; j < 16; ++j) { run *= (1.f - hv[j]); vprod[j] = run; }
        float x = run;
#pragma unroll
        for (int off = 1; off < 64; off <<= 1) {
            float o = __shfl_up(x, off, 64);
            if (lane >= off) x *= o;
        }
        float pre = __shfl_up(x, 1, 64);
        if (lane == 0) pre = 1.f;

        int p  = (int)trunc_s[row];
        int t0 = lane * 16;
        float sv[16];
#pragma unroll
        for (int j = 0; j < 16; ++j) {
            float s = pre * vprod[j];
            int t = t0 + j;
            if (t >= p) s *= __expf((float)(p - t));
            sv[j] = s;
        }
        float* Srow = out_S + (size_t)rowG * T_BINS + lane * 16;
        *(float4*)(Srow + 0)  = (float4){sv[0],  sv[1],  sv[2],  sv[3]};
        *(float4*)(Srow + 4)  = (float4){sv[4],  sv[5],  sv[6],  sv[7]};
        *(float4*)(Srow + 8)  = (float4){sv[8],  sv[9],  sv[10], sv[11]};
        *(float4*)(Srow + 12) = (float4){sv[12], sv[13], sv[14], sv[15]};
    }
}

// ---------------- R8 mega kernel (secondary path if ws fits only W; proven 190us) ----
__global__ __launch_bounds__(256, 2) void mega_kernel(
    const float* __restrict__ A, const _Float16* __restrict__ Wh,
    const float* __restrict__ bias, const float* __restrict__ labels,
    float* __restrict__ out_trunc, float* __restrict__ out_S,
    float* __restrict__ loss_acc)
{
    __shared__ _Float16 sA[2][64 * 64];      // 16 KB
    __shared__ _Float16 sW[2][256 * 64];     // 64 KB

    const int tid  = threadIdx.x;
    const int lane = tid & 63;
    const int wc   = tid >> 6;
    const int by   = blockIdx.x;

    const int arow = tid >> 2;
    const int ac   = tid & 3;
    const int x8a  = (arow ^ (arow >> 3)) & 7;
    const int sAw0 = arow * 64 + (((ac * 2) ^ x8a) * 8);
    const int sAw1 = arow * 64 + (((ac * 2 + 1) ^ x8a) * 8);
    const float* Abase = A + (size_t)(by * 64 + arow) * T_BINS + ac * 16;

    const int l3   = lane >> 3;
    const int wsl  = lane & 7;

    const int l15  = lane & 15;
    const int hi   = lane >> 4;
    const int xc   = (l15 & 7) ^ (l15 >> 3);

    float run_best[4][4];
    int   run_col[4][4];
#pragma unroll
    for (int i = 0; i < 4; ++i)
#pragma unroll
        for (int r = 0; r < 4; ++r) { run_best[i][r] = -3.4e38f; run_col[i][r] = 0; }

    {
        float4 f0 = *(const float4*)(Abase + 0);
        float4 f1 = *(const float4*)(Abase + 4);
        float4 f2 = *(const float4*)(Abase + 8);
        float4 f3 = *(const float4*)(Abase + 12);
        half8 h0, h1;
        h0[0] = (_Float16)f0.x; h0[1] = (_Float16)f0.y; h0[2] = (_Float16)f0.z; h0[3] = (_Float16)f0.w;
        h0[4] = (_Float16)f1.x; h0[5] = (_Float16)f1.y; h0[6] = (_Float16)f1.z; h0[7] = (_Float16)f1.w;
        h1[0] = (_Float16)f2.x; h1[1] = (_Float16)f2.y; h1[2] = (_Float16)f2.z; h1[3] = (_Float16)f2.w;
        h1[4] = (_Float16)f3.x; h1[5] = (_Float16)f3.y; h1[6] = (_Float16)f3.z; h1[7] = (_Float16)f3.w;
        *(half8*)&sA[0][sAw0] = h0;
        *(half8*)&sA[0][sAw1] = h1;
    }
#pragma unroll
    for (int r = 0; r < 8; ++r)
        async16h(Wh + (size_t)(wc * 64 + r * 8 + l3) * T_BINS + ((wsl ^ l3 ^ r) * 8),
                 &sW[0][(wc * 64 + r * 8) * 64]);
    float4 pa0 = *(const float4*)(Abase + 64);
    float4 pa1 = *(const float4*)(Abase + 68);
    float4 pa2 = *(const float4*)(Abase + 72);
    float4 pa3 = *(const float4*)(Abase + 76);
    __syncthreads();

    int n = 0;
    for (int bx = 0; bx < 4; ++bx) {
        const int colbase = bx * 256 + wc * 64 + l15;
        float bj[4];
#pragma unroll
        for (int j = 0; j < 4; ++j) bj[j] = bias[colbase + j * 16];

        floatx4 acc[4][4];
#pragma unroll
        for (int i = 0; i < 4; ++i)
#pragma unroll
            for (int j = 0; j < 4; ++j) acc[i][j] = (floatx4){0.f, 0.f, 0.f, 0.f};

        for (int t = 0; t < 16; ++t, ++n) {
            const int cur = n & 1;
            const int nxt = cur ^ 1;
            const int m   = (n + 1) & 63;
            const int bxn = m >> 4;
            const int k0n = (m & 15) * 64;

            const int kq = ((n + 2) & 15) * 64;
            float4 qa0 = *(const float4*)(Abase + kq + 0);
            float4 qa1 = *(const float4*)(Abase + kq + 4);
            float4 qa2 = *(const float4*)(Abase + kq + 8);
            float4 qa3 = *(const float4*)(Abase + kq + 12);

#pragma unroll
            for (int r = 0; r < 8; ++r)
                async16h(Wh + (size_t)(bxn * 256 + wc * 64 + r * 8 + l3) * T_BINS
                            + k0n + ((wsl ^ l3 ^ r) * 8),
                         &sW[nxt][(wc * 64 + r * 8) * 64]);

            {
                half8 h0, h1;
                h0[0] = (_Float16)pa0.x; h0[1] = (_Float16)pa0.y; h0[2] = (_Float16)pa0.z; h0[3] = (_Float16)pa0.w;
                h0[4] = (_Float16)pa1.x; h0[5] = (_Float16)pa1.y; h0[6] = (_Float16)pa1.z; h0[7] = (_Float16)pa1.w;
                h1[0] = (_Float16)pa2.x; h1[1] = (_Float16)pa2.y; h1[2] = (_Float16)pa2.z; h1[3] = (_Float16)pa2.w;
                h1[4] = (_Float16)pa3.x; h1[5] = (_Float16)pa3.y; h1[6] = (_Float16)pa3.z; h1[7] = (_Float16)pa3.w;
                *(half8*)&sA[nxt][sAw0] = h0;
                *(half8*)&sA[nxt][sAw1] = h1;
            }
            pa0 = qa0; pa1 = qa1; pa2 = qa2; pa3 = qa3;

#pragma unroll
            for (int g = 0; g < 2; ++g) {
                half8 ah[4], whf[4];
#pragma unroll
                for (int i = 0; i < 4; ++i)
                    ah[i] = *(const half8*)&sA[cur][(i * 16 + l15) * 64
                                                    + (((g * 4 + hi) ^ xc ^ (i * 2)) * 8)];
#pragma unroll
                for (int j = 0; j < 4; ++j)
                    whf[j] = *(const half8*)&sW[cur][(wc * 64 + j * 16 + l15) * 64
                                                     + (((g * 4 + hi) ^ xc ^ (j * 2)) * 8)];
#pragma unroll
                for (int i = 0; i < 4; ++i)
#pragma unroll
                    for (int j = 0; j < 4; ++j)
                        acc[i][j] = __builtin_amdgcn_mfma_f32_16x16x32_f16(ah[i], whf[j], acc[i][j], 0, 0, 0);
            }

            __syncthreads();
        }

#pragma unroll
        for (int i = 0; i < 4; ++i)
#pragma unroll
            for (int r = 0; r < 4; ++r)
#pragma unroll
                for (int j = 0; j < 4; ++j) {
                    float v = acc[i][j][r] + bj[j];
                    if (v > run_best[i][r]) { run_best[i][r] = v; run_col[i][r] = colbase + j * 16; }
                }
    }

    unsigned long long (*cand)[64] = reinterpret_cast<unsigned long long (*)[64]>(&sA[0][0]);
    float* trunc_s = reinterpret_cast<float*>(&sA[0][0]) + 512;

#pragma unroll
    for (int i = 0; i < 4; ++i)
#pragma unroll
        for (int r = 0; r < 4; ++r) {
            float best = run_best[i][r];
            int   bc   = run_col[i][r];
#pragma unroll
            for (int off = 8; off >= 1; off >>= 1) {
                float ov = __shfl_xor(best, off, 64);
                int   oc = __shfl_xor(bc, off, 64);
                if (ov > best || (ov == best && oc < bc)) { best = ov; bc = oc; }
            }
            if ((lane & 15) == 0)
                cand[wc][i * 16 + (lane >> 4) * 4 + r] = pack_max(best, bc);
        }
    __syncthreads();

    if (tid < 64) {
        unsigned long long m01 = cand[0][tid] > cand[1][tid] ? cand[0][tid] : cand[1][tid];
        unsigned long long m23 = cand[2][tid] > cand[3][tid] ? cand[2][tid] : cand[3][tid];
        unsigned long long mm = m01 > m23 ? m01 : m23;
        unsigned col = ~(unsigned)mm;
        float p = (float)col;
        int rowG = by * 64 + tid;
        out_trunc[rowG] = p;
        trunc_s[tid] = p;
        float d = p - labels[rowG];
        float term = d * d * (1.0f / (float)B_ROWS);
#pragma unroll
        for (int off = 32; off >= 1; off >>= 1)
            term += __shfl_down(term, off, 64);
        if (tid == 0) atomicAdd(loss_acc, term);
    }
    __syncthreads();

    for (int rr = 0; rr < 16; ++rr) {
        int row  = wc * 16 + rr;
        int rowG = by * 64 + row;
        const float* Hrow = A + (size_t)rowG * T_BINS + lane * 16;
        float4 h0 = *(const float4*)(Hrow + 0);
        float4 h1 = *(const float4*)(Hrow + 4);
        float4 h2 = *(const float4*)(Hrow + 8);
        float4 h3 = *(const float4*)(Hrow + 12);
        float hv[16] = {h0.x, h0.y, h0.z, h0.w, h1.x, h1.y, h1.z, h1.w,
                        h2.x, h2.y, h2.z, h2.w, h3.x, h3.y, h3.z, h3.w};
        float vprod[16];
        float run = 1.f;
#pragma unroll
        for (int j = 0; j < 16; ++j) { run *= (1.f - hv[j]); vprod[j] = run; }
        float x = run;
#pragma unroll
        for (int off = 1; off < 64; off <<= 1) {
            float o = __shfl_up(x, off, 64);
            if (lane >= off) x *= o;
        }
        float pre = __shfl_up(x, 1, 64);
        if (lane == 0) pre = 1.f;

        int p  = (int)trunc_s[row];
        int t0 = lane * 16;
        float sv[16];
#pragma unroll
        for (int j = 0; j < 16; ++j) {
            float s = pre * vprod[j];
            int t = t0 + j;
            if (t >= p) s *= __expf((float)(p - t));
            sv[j] = s;
        }
        float* Srow = out_S + (size_t)rowG * T_BINS + lane * 16;
        *(float4*)(Srow + 0)  = (float4){sv[0],  sv[1],  sv[2],  sv[3]};
        *(float4*)(Srow + 4)  = (float4){sv[4],  sv[5],  sv[6],  sv[7]};
        *(float4*)(Srow + 8)  = (float4){sv[8],  sv[9],  sv[10], sv[11]};
        *(float4*)(Srow + 12) = (float4){sv[12], sv[13], sv[14], sv[15]};
    }
}

// ---------------- fp32 fallback path (round-1 kernels), used if ws too small ----------------
#define BMf 64
#define BKf 16
#define LDSS (BMf + 4)
__global__ __launch_bounds__(256) void gemm_argmax_fp32(
    const float* __restrict__ A, const float* __restrict__ W,
    const float* __restrict__ bias, unsigned long long* __restrict__ rec)
{
    __shared__ float As[BKf][LDSS];
    __shared__ float Ws[BKf][LDSS];
    const int tid = threadIdx.x;
    const int tx = tid & 15, ty = tid >> 4;
    const int bx = blockIdx.x, by = blockIdx.y;
    const int ar = tid >> 2, ak = (tid & 3) << 2;
    const float* Arow = A + (size_t)(by * BMf + ar) * T_BINS + ak;
    const float* Wrow = W + (size_t)(bx * BMf + ar) * T_BINS + ak;
    float acc[4][4];
#pragma unroll
    for (int i = 0; i < 4; ++i)
#pragma unroll
        for (int j = 0; j < 4; ++j) acc[i][j] = 0.f;
    for (int k0 = 0; k0 < T_BINS; k0 += BKf) {
        float4 av = *(const float4*)(Arow + k0);
        float4 wvv = *(const float4*)(Wrow + k0);
        As[ak + 0][ar] = av.x; As[ak + 1][ar] = av.y; As[ak + 2][ar] = av.z; As[ak + 3][ar] = av.w;
        Ws[ak + 0][ar] = wvv.x; Ws[ak + 1][ar] = wvv.y; Ws[ak + 2][ar] = wvv.z; Ws[ak + 3][ar] = wvv.w;
        __syncthreads();
#pragma unroll
        for (int k = 0; k < BKf; ++k) {
            float4 a4 = *(const float4*)&As[k][ty * 4];
            float4 w4 = *(const float4*)&Ws[k][tx * 4];
            float aa[4] = {a4.x, a4.y, a4.z, a4.w};
            float ww[4] = {w4.x, w4.y, w4.z, w4.w};
#pragma unroll
            for (int i = 0; i < 4; ++i)
#pragma unroll
                for (int j = 0; j < 4; ++j) acc[i][j] = fmaf(aa[i], ww[j], acc[i][j]);
        }
        __syncthreads();
    }
    const int colBase = bx * BMf + tx * 4;
    float bv[4];
#pragma unroll
    for (int j = 0; j < 4; ++j) bv[j] = bias[colBase + j];
#pragma unroll
    for (int i = 0; i < 4; ++i) {
        float best = acc[i][0] + bv[0];
        int bc = colBase;
#pragma unroll
        for (int j = 1; j < 4; ++j) {
            float v = acc[i][j] + bv[j];
            if (v > best) { best = v; bc = colBase + j; }
        }
#pragma unroll
        for (int off = 8; off >= 1; off >>= 1) {
            float ov = __shfl_xor(best, off, 64);
            int oc = __shfl_xor(bc, off, 64);
            if (ov > best || (ov == best && oc < bc)) { best = ov; bc = oc; }
        }
        if (tx == 0) atomicMax(&rec[by * BMf + ty * 4 + i], pack_max(best, bc));
    }
}

__global__ __launch_bounds__(256) void finalize_kernel(
    const unsigned long long* __restrict__ rec, const float* __restrict__ labels,
    float* __restrict__ out_trunc, float* __restrict__ loss_acc)
{
    int i = blockIdx.x * 256 + threadIdx.x;
    unsigned col = ~(unsigned)(rec[i] & 0xFFFFFFFFull);
    float p = (float)col;
    out_trunc[i] = p;
    float d = p - labels[i];
    float term = d * d * (1.0f / (float)B_ROWS);
#pragma unroll
    for (int off = 32; off >= 1; off >>= 1)
        term += __shfl_down(term, off, 64);
    __shared__ float partials[4];
    int lane = threadIdx.x & 63, wv = threadIdx.x >> 6;
    if (lane == 0) partials[wv] = term;
    __syncthreads();
    if (threadIdx.x == 0)
        atomicAdd(loss_acc, partials[0] + partials[1] + partials[2] + partials[3]);
}

__global__ __launch_bounds__(256) void scan_kernel_f32(
    const float* __restrict__ H, const float* __restrict__ trunc_f,
    float* __restrict__ Sout)
{
    const int row = blockIdx.x;
    const int tid = threadIdx.x;
    const int lane = tid & 63;
    const int wv = tid >> 6;
    const float4 h = *(const float4*)(H + (size_t)row * T_BINS + tid * 4);
    float l0 = 1.f - h.x;
    float l1 = l0 * (1.f - h.y);
    float l2 = l1 * (1.f - h.z);
    float l3 = l2 * (1.f - h.w);
    float x = l3;
#pragma unroll
    for (int off = 1; off < 64; off <<= 1) {
        float o = __shfl_up(x, off, 64);
        if (lane >= off) x *= o;
    }
    float ex = __shfl_up(x, 1, 64);
    if (lane == 0) ex = 1.f;
    __shared__ float wtot[4];
    if (lane == 63) wtot[wv] = x;
    __syncthreads();
    float wpre = 1.f;
#pragma unroll
    for (int w = 0; w < 3; ++w)
        if (w < wv) wpre *= wtot[w];
    float pre = wpre * ex;
    int p = (int)trunc_f[row];
    int t0 = tid * 4;
    float sv[4] = {pre * l0, pre * l1, pre * l2, pre * l3};
#pragma unroll
    for (int j = 0; j < 4; ++j) {
        int t = t0 + j;
        if (t >= p) sv[j] *= __expf((float)(p - t));
    }
    float4 s4 = {sv[0], sv[1], sv[2], sv[3]};
    *(float4*)(Sout + (size_t)row * T_BINS + tid * 4) = s4;
}

extern "C" void kernel_launch(void* const* d_in, const int* in_sizes, int n_in,
                              void* d_out, int out_size, void* d_ws, size_t ws_size,
                              hipStream_t stream)
{
    const float* hazard = (const float*)d_in[0];   // [B, T]
    const float* labels = (const float*)d_in[1];   // [B]
    const float* W      = (const float*)d_in[2];   // [T, T]
    const float* bias   = (const float*)d_in[3];   // [T]

    float* out       = (float*)d_out;
    float* out_trunc = out;                                       // B floats
    float* out_S     = out + B_ROWS;                              // B*T floats
    float* out_loss  = out + B_ROWS + (size_t)B_ROWS * T_BINS;    // 1 float

    hipMemsetAsync(out_loss, 0, sizeof(float), stream);

    const size_t NW = (size_t)T_BINS * T_BINS;
    const size_t wh_bytes  = NW * sizeof(_Float16);
    const size_t rec_bytes = (size_t)B_ROWS * sizeof(unsigned long long);

    if (ws_size >= wh_bytes + rec_bytes) {
        // R10 split path: 128x512-tile f16 GEMM (atomicMax rec in ws) + fused finscan
        _Float16* Wh = (_Float16*)d_ws;
        unsigned long long* rec = (unsigned long long*)((char*)d_ws + wh_bytes);
        hipMemsetAsync(rec, 0, rec_bytes, stream);
        tof16_kernel<<<(int)(NW / 4 / 256), 256, 0, stream>>>(W, Wh, (int)(NW / 4));
        gemm_argmax_f16<<<512, 256, 0, stream>>>(hazard, Wh, bias, rec);
        finscan_kernel<<<512, 256, 0, stream>>>(hazard, rec, labels, out_trunc, out_S, out_loss);
    } else if (ws_size >= wh_bytes) {
        // R8 fused mega (proven 190us)
        _Float16* Wh = (_Float16*)d_ws;
        tof16_kernel<<<(int)(NW / 4 / 256), 256, 0, stream>>>(W, Wh, (int)(NW / 4));
        mega_kernel<<<B_ROWS / 64, 256, 0, stream>>>(
            hazard, Wh, bias, labels, out_trunc, out_S, out_loss);
    } else {
        unsigned long long* rec = (unsigned long long*)out_S;
        hipMemsetAsync(rec, 0, (size_t)B_ROWS * sizeof(unsigned long long), stream);
        dim3 ggrid(T_BINS / BMf, B_ROWS / BMf);
        gemm_argmax_fp32<<<ggrid, 256, 0, stream>>>(hazard, W, bias, rec);
        finalize_kernel<<<B_ROWS / 256, 256, 0, stream>>>(rec, labels, out_trunc, out_loss);
        scan_kernel_f32<<<B_ROWS, 256, 0, stream>>>(hazard, out_trunc, out_S);
    }
}

// Round 7
// 354.053 us; speedup vs baseline: 1.3029x; 1.3029x over previous
//
#include <hip/hip_runtime.h>

#define B_ROWS 32768
#define T_BINS 1024

typedef __attribute__((ext_vector_type(8))) _Float16 half8;
typedef __attribute__((ext_vector_type(4))) float floatx4;

__device__ __forceinline__ unsigned long long pack_max(float v, int col) {
    unsigned x = __float_as_uint(v);
    x = (x & 0x80000000u) ? ~x : (x | 0x80000000u);   // monotone float->uint
    return ((unsigned long long)x << 32) | (unsigned)(~col);  // ties -> smaller col
}

__device__ __forceinline__ void async16h(const _Float16* g, _Float16* l) {
    __builtin_amdgcn_global_load_lds(
        (const __attribute__((address_space(1))) unsigned int*)g,
        (__attribute__((address_space(3))) unsigned int*)l,
        16, 0, 0);
}

// ---------------- convert fp32 -> f16 (RNE), used for W only ----------------
__global__ __launch_bounds__(256) void tof16_kernel(
    const float* __restrict__ src, _Float16* __restrict__ dst, int n4)
{
    int idx = blockIdx.x * 256 + threadIdx.x;
    if (idx >= n4) return;
    float4 x = ((const float4*)src)[idx];
    union { _Float16 h[4]; ushort4 u; } cv;
    cv.h[0] = (_Float16)x.x;
    cv.h[1] = (_Float16)x.y;
    cv.h[2] = (_Float16)x.z;
    cv.h[3] = (_Float16)x.w;
    ((ushort4*)dst)[idx] = cv.u;
}

// ---------------- MEGA (R8 structure, proven 190us / 352.8 total) ----------------
// R11 = R8 restored as primary after R9/R10 restructures regressed (169/264us GEMM).
// Ledger: staged bytes per block A 1MB(f32) + W 2MB(f16) = 3MB, c=2 blocks/CU (grid
// 512), 64 fat slots (BK=64, 32 MFMA/wave/slot), single __syncthreads per slot.
// R11 micro-deltas vs R8 (both zero-risk):
//  (a) W asyncs issued BEFORE the A reg-loads in each slot — the barrier drains the
//      asyncs, so start them earlier; no data dependence between the two groups.
//  (b) skip staging on the last slot (n==63 staged a wrapped tile nobody reads).
__global__ __launch_bounds__(256, 2) void mega_kernel(
    const float* __restrict__ A, const _Float16* __restrict__ Wh,
    const float* __restrict__ bias, const float* __restrict__ labels,
    float* __restrict__ out_trunc, float* __restrict__ out_S,
    float* __restrict__ loss_acc)
{
    __shared__ _Float16 sA[2][64 * 64];      // 16 KB
    __shared__ _Float16 sW[2][256 * 64];     // 64 KB

    const int tid  = threadIdx.x;
    const int lane = tid & 63;
    const int wc   = tid >> 6;      // wave = column group 0..3
    const int by   = blockIdx.x;    // row slab 0..511

    // ---- A staging: thread -> (row=tid>>2, 16-float chunk ac=tid&3) -> two half8
    //      ds_writes at 16B slots (2ac)^x8(row), (2ac+1)^x8(row), x8(r)=(r^(r>>3))&7
    const int arow = tid >> 2;                 // 0..63
    const int ac   = tid & 3;                  // 0..3
    const int x8a  = (arow ^ (arow >> 3)) & 7;
    const int sAw0 = arow * 64 + (((ac * 2) ^ x8a) * 8);       // halfs
    const int sAw1 = arow * 64 + (((ac * 2 + 1) ^ x8a) * 8);   // halfs
    const float* Abase = A + (size_t)(by * 64 + arow) * T_BINS + ac * 16;

    // ---- W staging: 8 asyncs/wave; async r covers cols wc*64+r*8 .. +8; swizzle
    //      folded into global src k-offset: src chunk = (l&7) ^ (l>>3) ^ r
    const int l3   = lane >> 3;    // 0..7
    const int wsl  = lane & 7;     // 0..7

    // ---- fragment reads: logical slot g*4+hi -> phys (g*4+hi) ^ xc ^ (i*2 or j*2)
    const int l15  = lane & 15;
    const int hi   = lane >> 4;
    const int xc   = (l15 & 7) ^ (l15 >> 3);

    float run_best[4][4];
    int   run_col[4][4];
#pragma unroll
    for (int i = 0; i < 4; ++i)
#pragma unroll
        for (int r = 0; r < 4; ++r) { run_best[i][r] = -3.4e38f; run_col[i][r] = 0; }

    // ---- prologue: stage tile 0 into buf 0; prefetch A regs for tile 1 ----
    {
        float4 f0 = *(const float4*)(Abase + 0);
        float4 f1 = *(const float4*)(Abase + 4);
        float4 f2 = *(const float4*)(Abase + 8);
        float4 f3 = *(const float4*)(Abase + 12);
        half8 h0, h1;
        h0[0] = (_Float16)f0.x; h0[1] = (_Float16)f0.y; h0[2] = (_Float16)f0.z; h0[3] = (_Float16)f0.w;
        h0[4] = (_Float16)f1.x; h0[5] = (_Float16)f1.y; h0[6] = (_Float16)f1.z; h0[7] = (_Float16)f1.w;
        h1[0] = (_Float16)f2.x; h1[1] = (_Float16)f2.y; h1[2] = (_Float16)f2.z; h1[3] = (_Float16)f2.w;
        h1[4] = (_Float16)f3.x; h1[5] = (_Float16)f3.y; h1[6] = (_Float16)f3.z; h1[7] = (_Float16)f3.w;
        *(half8*)&sA[0][sAw0] = h0;
        *(half8*)&sA[0][sAw1] = h1;
    }
#pragma unroll
    for (int r = 0; r < 8; ++r)
        async16h(Wh + (size_t)(wc * 64 + r * 8 + l3) * T_BINS + ((wsl ^ l3 ^ r) * 8),
                 &sW[0][(wc * 64 + r * 8) * 64]);
    float4 pa0 = *(const float4*)(Abase + 64);
    float4 pa1 = *(const float4*)(Abase + 68);
    float4 pa2 = *(const float4*)(Abase + 72);
    float4 pa3 = *(const float4*)(Abase + 76);
    __syncthreads();

    // ---- main loop: 64 tiles (4 bx x 16 k-steps of BK=64), double-buffered ----
    int n = 0;
    for (int bx = 0; bx < 4; ++bx) {
        const int colbase = bx * 256 + wc * 64 + l15;
        float bj[4];
#pragma unroll
        for (int j = 0; j < 4; ++j) bj[j] = bias[colbase + j * 16];

        floatx4 acc[4][4];
#pragma unroll
        for (int i = 0; i < 4; ++i)
#pragma unroll
            for (int j = 0; j < 4; ++j) acc[i][j] = (floatx4){0.f, 0.f, 0.f, 0.f};

        for (int t = 0; t < 16; ++t, ++n) {
            const int cur = n & 1;
            const int nxt = cur ^ 1;

            if (n < 63) {   // (b) last slot: nothing left to stage
                const int m   = n + 1;
                const int bxn = m >> 4;
                const int k0n = (m & 15) * 64;

                // (a) 1. W asyncs for tile n+1 first — these are what the barrier
                //     drains; give them the whole slot to land.
#pragma unroll
                for (int r = 0; r < 8; ++r)
                    async16h(Wh + (size_t)(bxn * 256 + wc * 64 + r * 8 + l3) * T_BINS
                                + k0n + ((wsl ^ l3 ^ r) * 8),
                             &sW[nxt][(wc * 64 + r * 8) * 64]);

                // 2. prefetch A regs for tile n+2 (A depends only on k)
                const int kq = ((n + 2) & 15) * 64;
                float4 qa0 = *(const float4*)(Abase + kq + 0);
                float4 qa1 = *(const float4*)(Abase + kq + 4);
                float4 qa2 = *(const float4*)(Abase + kq + 8);
                float4 qa3 = *(const float4*)(Abase + kq + 12);

                // 3. stage A(n+1) from regs into the other buffer (swizzled slots)
                {
                    half8 h0, h1;
                    h0[0] = (_Float16)pa0.x; h0[1] = (_Float16)pa0.y; h0[2] = (_Float16)pa0.z; h0[3] = (_Float16)pa0.w;
                    h0[4] = (_Float16)pa1.x; h0[5] = (_Float16)pa1.y; h0[6] = (_Float16)pa1.z; h0[7] = (_Float16)pa1.w;
                    h1[0] = (_Float16)pa2.x; h1[1] = (_Float16)pa2.y; h1[2] = (_Float16)pa2.z; h1[3] = (_Float16)pa2.w;
                    h1[4] = (_Float16)pa3.x; h1[5] = (_Float16)pa3.y; h1[6] = (_Float16)pa3.z; h1[7] = (_Float16)pa3.w;
                    *(half8*)&sA[nxt][sAw0] = h0;
                    *(half8*)&sA[nxt][sAw1] = h1;
                }
                pa0 = qa0; pa1 = qa1; pa2 = qa2; pa3 = qa3;
            }

            // 4. fragments + MFMA on current buffers: 2 k-subtiles x 16 MFMA
#pragma unroll
            for (int g = 0; g < 2; ++g) {
                half8 ah[4], whf[4];
#pragma unroll
                for (int i = 0; i < 4; ++i)
                    ah[i] = *(const half8*)&sA[cur][(i * 16 + l15) * 64
                                                    + (((g * 4 + hi) ^ xc ^ (i * 2)) * 8)];
#pragma unroll
                for (int j = 0; j < 4; ++j)
                    whf[j] = *(const half8*)&sW[cur][(wc * 64 + j * 16 + l15) * 64
                                                     + (((g * 4 + hi) ^ xc ^ (j * 2)) * 8)];
#pragma unroll
                for (int i = 0; i < 4; ++i)
#pragma unroll
                    for (int j = 0; j < 4; ++j)
                        acc[i][j] = __builtin_amdgcn_mfma_f32_16x16x32_f16(ah[i], whf[j], acc[i][j], 0, 0, 0);
            }

            // 5. barrier: guards buffer swap (drains asyncs + ds_writes + prefetches)
            __syncthreads();
        }

        // fold this bx's acc into the running argmax (cols strictly increase)
#pragma unroll
        for (int i = 0; i < 4; ++i)
#pragma unroll
            for (int r = 0; r < 4; ++r)
#pragma unroll
                for (int j = 0; j < 4; ++j) {
                    float v = acc[i][j][r] + bj[j];
                    if (v > run_best[i][r]) { run_best[i][r] = v; run_col[i][r] = colbase + j * 16; }
                }
    }

    // ---- epilogue: cand/trunc overlaid on dead sA (keeps LDS at 80KB) ----
    unsigned long long (*cand)[64] = reinterpret_cast<unsigned long long (*)[64]>(&sA[0][0]);
    float* trunc_s = reinterpret_cast<float*>(&sA[0][0]) + 512;   // bytes 2048..2303

    // 16-lane (column-lane) reduce; lanes {0,16,32,48} publish per-row candidates
#pragma unroll
    for (int i = 0; i < 4; ++i)
#pragma unroll
        for (int r = 0; r < 4; ++r) {
            float best = run_best[i][r];
            int   bc   = run_col[i][r];
#pragma unroll
            for (int off = 8; off >= 1; off >>= 1) {
                float ov = __shfl_xor(best, off, 64);
                int   oc = __shfl_xor(bc, off, 64);
                if (ov > best || (ov == best && oc < bc)) { best = ov; bc = oc; }
            }
            if ((lane & 15) == 0)
                cand[wc][i * 16 + (lane >> 4) * 4 + r] = pack_max(best, bc);
        }
    __syncthreads();

    // wave 0: combine 4 col-group candidates per row, write trunc_pos + loss
    if (tid < 64) {
        unsigned long long m01 = cand[0][tid] > cand[1][tid] ? cand[0][tid] : cand[1][tid];
        unsigned long long m23 = cand[2][tid] > cand[3][tid] ? cand[2][tid] : cand[3][tid];
        unsigned long long mm = m01 > m23 ? m01 : m23;
        unsigned col = ~(unsigned)mm;
        float p = (float)col;
        int rowG = by * 64 + tid;
        out_trunc[rowG] = p;
        trunc_s[tid] = p;
        float d = p - labels[rowG];
        float term = d * d * (1.0f / (float)B_ROWS);
#pragma unroll
        for (int off = 32; off >= 1; off >>= 1)
            term += __shfl_down(term, off, 64);
        if (tid == 0) atomicAdd(loss_acc, term);
    }
    __syncthreads();

    // scan phase: wave wc handles rows wc*16 .. wc*16+15; lane covers 16 elements
    for (int rr = 0; rr < 16; ++rr) {
        int row  = wc * 16 + rr;
        int rowG = by * 64 + row;
        const float* Hrow = A + (size_t)rowG * T_BINS + lane * 16;
        float4 h0 = *(const float4*)(Hrow + 0);
        float4 h1 = *(const float4*)(Hrow + 4);
        float4 h2 = *(const float4*)(Hrow + 8);
        float4 h3 = *(const float4*)(Hrow + 12);
        float hv[16] = {h0.x, h0.y, h0.z, h0.w, h1.x, h1.y, h1.z, h1.w,
                        h2.x, h2.y, h2.z, h2.w, h3.x, h3.y, h3.z, h3.w};
        float vprod[16];
        float run = 1.f;
#pragma unroll
        for (int j = 0; j < 16; ++j) { run *= (1.f - hv[j]); vprod[j] = run; }
        float x = run;
#pragma unroll
        for (int off = 1; off < 64; off <<= 1) {
            float o = __shfl_up(x, off, 64);
            if (lane >= off) x *= o;
        }
        float pre = __shfl_up(x, 1, 64);
        if (lane == 0) pre = 1.f;

        int p  = (int)trunc_s[row];
        int t0 = lane * 16;
        float sv[16];
#pragma unroll
        for (int j = 0; j < 16; ++j) {
            float s = pre * vprod[j];
            int t = t0 + j;
            if (t >= p) s *= __expf((float)(p - t));
            sv[j] = s;
        }
        float* Srow = out_S + (size_t)rowG * T_BINS + lane * 16;
        *(float4*)(Srow + 0)  = (float4){sv[0],  sv[1],  sv[2],  sv[3]};
        *(float4*)(Srow + 4)  = (float4){sv[4],  sv[5],  sv[6],  sv[7]};
        *(float4*)(Srow + 8)  = (float4){sv[8],  sv[9],  sv[10], sv[11]};
        *(float4*)(Srow + 12) = (float4){sv[12], sv[13], sv[14], sv[15]};
    }
}

// ---------------- fp32 fallback path (round-1 kernels), used if ws too small ----------------
#define BMf 64
#define BKf 16
#define LDSS (BMf + 4)
__global__ __launch_bounds__(256) void gemm_argmax_fp32(
    const float* __restrict__ A, const float* __restrict__ W,
    const float* __restrict__ bias, unsigned long long* __restrict__ rec)
{
    __shared__ float As[BKf][LDSS];
    __shared__ float Ws[BKf][LDSS];
    const int tid = threadIdx.x;
    const int tx = tid & 15, ty = tid >> 4;
    const int bx = blockIdx.x, by = blockIdx.y;
    const int ar = tid >> 2, ak = (tid & 3) << 2;
    const float* Arow = A + (size_t)(by * BMf + ar) * T_BINS + ak;
    const float* Wrow = W + (size_t)(bx * BMf + ar) * T_BINS + ak;
    float acc[4][4];
#pragma unroll
    for (int i = 0; i < 4; ++i)
#pragma unroll
        for (int j = 0; j < 4; ++j) acc[i][j] = 0.f;
    for (int k0 = 0; k0 < T_BINS; k0 += BKf) {
        float4 av = *(const float4*)(Arow + k0);
        float4 wvv = *(const float4*)(Wrow + k0);
        As[ak + 0][ar] = av.x; As[ak + 1][ar] = av.y; As[ak + 2][ar] = av.z; As[ak + 3][ar] = av.w;
        Ws[ak + 0][ar] = wvv.x; Ws[ak + 1][ar] = wvv.y; Ws[ak + 2][ar] = wvv.z; Ws[ak + 3][ar] = wvv.w;
        __syncthreads();
#pragma unroll
        for (int k = 0; k < BKf; ++k) {
            float4 a4 = *(const float4*)&As[k][ty * 4];
            float4 w4 = *(const float4*)&Ws[k][tx * 4];
            float aa[4] = {a4.x, a4.y, a4.z, a4.w};
            float ww[4] = {w4.x, w4.y, w4.z, w4.w};
#pragma unroll
            for (int i = 0; i < 4; ++i)
#pragma unroll
                for (int j = 0; j < 4; ++j) acc[i][j] = fmaf(aa[i], ww[j], acc[i][j]);
        }
        __syncthreads();
    }
    const int colBase = bx * BMf + tx * 4;
    float bv[4];
#pragma unroll
    for (int j = 0; j < 4; ++j) bv[j] = bias[colBase + j];
#pragma unroll
    for (int i = 0; i < 4; ++i) {
        float best = acc[i][0] + bv[0];
        int bc = colBase;
#pragma unroll
        for (int j = 1; j < 4; ++j) {
            float v = acc[i][j] + bv[j];
            if (v > best) { best = v; bc = colBase + j; }
        }
#pragma unroll
        for (int off = 8; off >= 1; off >>= 1) {
            float ov = __shfl_xor(best, off, 64);
            int oc = __shfl_xor(bc, off, 64);
            if (ov > best || (ov == best && oc < bc)) { best = ov; bc = oc; }
        }
        if (tx == 0) atomicMax(&rec[by * BMf + ty * 4 + i], pack_max(best, bc));
    }
}

__global__ __launch_bounds__(256) void finalize_kernel(
    const unsigned long long* __restrict__ rec, const float* __restrict__ labels,
    float* __restrict__ out_trunc, float* __restrict__ loss_acc)
{
    int i = blockIdx.x * 256 + threadIdx.x;
    unsigned col = ~(unsigned)(rec[i] & 0xFFFFFFFFull);
    float p = (float)col;
    out_trunc[i] = p;
    float d = p - labels[i];
    float term = d * d * (1.0f / (float)B_ROWS);
#pragma unroll
    for (int off = 32; off >= 1; off >>= 1)
        term += __shfl_down(term, off, 64);
    __shared__ float partials[4];
    int lane = threadIdx.x & 63, wv = threadIdx.x >> 6;
    if (lane == 0) partials[wv] = term;
    __syncthreads();
    if (threadIdx.x == 0)
        atomicAdd(loss_acc, partials[0] + partials[1] + partials[2] + partials[3]);
}

__global__ __launch_bounds__(256) void scan_kernel_f32(
    const float* __restrict__ H, const float* __restrict__ trunc_f,
    float* __restrict__ Sout)
{
    const int row = blockIdx.x;
    const int tid = threadIdx.x;
    const int lane = tid & 63;
    const int wv = tid >> 6;
    const float4 h = *(const float4*)(H + (size_t)row * T_BINS + tid * 4);
    float l0 = 1.f - h.x;
    float l1 = l0 * (1.f - h.y);
    float l2 = l1 * (1.f - h.z);
    float l3 = l2 * (1.f - h.w);
    float x = l3;
#pragma unroll
    for (int off = 1; off < 64; off <<= 1) {
        float o = __shfl_up(x, off, 64);
        if (lane >= off) x *= o;
    }
    float ex = __shfl_up(x, 1, 64);
    if (lane == 0) ex = 1.f;
    __shared__ float wtot[4];
    if (lane == 63) wtot[wv] = x;
    __syncthreads();
    float wpre = 1.f;
#pragma unroll
    for (int w = 0; w < 3; ++w)
        if (w < wv) wpre *= wtot[w];
    float pre = wpre * ex;
    int p = (int)trunc_f[row];
    int t0 = tid * 4;
    float sv[4] = {pre * l0, pre * l1, pre * l2, pre * l3};
#pragma unroll
    for (int j = 0; j < 4; ++j) {
        int t = t0 + j;
        if (t >= p) sv[j] *= __expf((float)(p - t));
    }
    float4 s4 = {sv[0], sv[1], sv[2], sv[3]};
    *(float4*)(Sout + (size_t)row * T_BINS + tid * 4) = s4;
}

extern "C" void kernel_launch(void* const* d_in, const int* in_sizes, int n_in,
                              void* d_out, int out_size, void* d_ws, size_t ws_size,
                              hipStream_t stream)
{
    const float* hazard = (const float*)d_in[0];   // [B, T]
    const float* labels = (const float*)d_in[1];   // [B]
    const float* W      = (const float*)d_in[2];   // [T, T]
    const float* bias   = (const float*)d_in[3];   // [T]

    float* out       = (float*)d_out;
    float* out_trunc = out;                                       // B floats
    float* out_S     = out + B_ROWS;                              // B*T floats
    float* out_loss  = out + B_ROWS + (size_t)B_ROWS * T_BINS;    // 1 float

    hipMemsetAsync(out_loss, 0, sizeof(float), stream);

    const size_t NW = (size_t)T_BINS * T_BINS;
    if (ws_size >= NW * sizeof(_Float16)) {
        // R8 fused mega (proven best: 190us kernel, 352.8us total)
        _Float16* Wh = (_Float16*)d_ws;
        tof16_kernel<<<(int)(NW / 4 / 256), 256, 0, stream>>>(W, Wh, (int)(NW / 4));
        mega_kernel<<<B_ROWS / 64, 256, 0, stream>>>(
            hazard, Wh, bias, labels, out_trunc, out_S, out_loss);
    } else {
        unsigned long long* rec = (unsigned long long*)out_S;
        hipMemsetAsync(rec, 0, (size_t)B_ROWS * sizeof(unsigned long long), stream);
        dim3 ggrid(T_BINS / BMf, B_ROWS / BMf);
        gemm_argmax_fp32<<<ggrid, 256, 0, stream>>>(hazard, W, bias, rec);
        finalize_kernel<<<B_ROWS / 256, 256, 0, stream>>>(rec, labels, out_trunc, out_loss);
        scan_kernel_f32<<<B_ROWS, 256, 0, stream>>>(hazard, out_trunc, out_S);
    }
}

// Round 8
// 345.826 us; speedup vs baseline: 1.3339x; 1.0238x over previous
//
#include <hip/hip_runtime.h>

#define B_ROWS 32768
#define T_BINS 1024

typedef __attribute__((ext_vector_type(8))) _Float16 half8;
typedef __attribute__((ext_vector_type(4))) float floatx4;

__device__ __forceinline__ unsigned long long pack_max(float v, int col) {
    unsigned x = __float_as_uint(v);
    x = (x & 0x80000000u) ? ~x : (x | 0x80000000u);   // monotone float->uint
    return ((unsigned long long)x << 32) | (unsigned)(~col);  // ties -> smaller col
}

__device__ __forceinline__ void async16h(const _Float16* g, _Float16* l) {
    __builtin_amdgcn_global_load_lds(
        (const __attribute__((address_space(1))) unsigned int*)g,
        (__attribute__((address_space(3))) unsigned int*)l,
        16, 0, 0);
}

// ---------------- convert fp32 -> f16 (RNE), used for W only ----------------
__global__ __launch_bounds__(256) void tof16_kernel(
    const float* __restrict__ src, _Float16* __restrict__ dst, int n4)
{
    int idx = blockIdx.x * 256 + threadIdx.x;
    if (idx >= n4) return;
    float4 x = ((const float4*)src)[idx];
    union { _Float16 h[4]; ushort4 u; } cv;
    cv.h[0] = (_Float16)x.x;
    cv.h[1] = (_Float16)x.y;
    cv.h[2] = (_Float16)x.z;
    cv.h[3] = (_Float16)x.w;
    ((ushort4*)dst)[idx] = cv.u;
}

// ---------------- MEGA R12: R8 geometry, 8 waves/block (TLP experiment) ----------------
// R8/R11 profile: GEMM phase ~136us, per-slot wall ~5000cyc vs ~600cyc issued work;
// no roofline saturated (HBM 15%, L2 22%, MFMA 15%) at 2 waves/SIMD -> latency-bound
// hypothesis. R12 = identical staged bytes / slots / barriers / LDS (M=64, BK=64,
// grid 512, 80KB, c=2 blocks/CU) but 512 threads = 8 waves -> 4 waves/SIMD.
// Per-wave: 4 W-asyncs (cols w*32..+32, self-staged), acc[4][2] (32 f32), 16 MFMA +
// 6 ds_read_b128 per slot. XOR swizzle as R8 with wave bit (w&1)*4 folded in.
__global__ __launch_bounds__(512, 4) void mega_kernel(
    const float* __restrict__ A, const _Float16* __restrict__ Wh,
    const float* __restrict__ bias, const float* __restrict__ labels,
    float* __restrict__ out_trunc, float* __restrict__ out_S,
    float* __restrict__ loss_acc)
{
    __shared__ _Float16 sA[2][64 * 64];      // 16 KB
    __shared__ _Float16 sW[2][256 * 64];     // 64 KB

    const int tid  = threadIdx.x;            // 0..511
    const int lane = tid & 63;
    const int w    = tid >> 6;               // wave 0..7 = 32-col group per stage
    const int by   = blockIdx.x;             // row slab 0..511

    // ---- A staging: thread -> (row=tid>>3, phys slot c8=tid&7), ONE half8 write;
    //      phys slot c8 holds source chunk c8^x8(row), x8(r)=(r^(r>>3))&7
    const int arow = tid >> 3;               // 0..63
    const int c8   = tid & 7;                // 0..7
    const int x8a  = (arow ^ (arow >> 3)) & 7;
    const int asc  = c8 ^ x8a;               // source k-chunk
    const float* Abase = A + (size_t)(by * 64 + arow) * T_BINS + asc * 8;
    const int sAw  = arow * 64 + c8 * 8;     // halfs

    // ---- W staging: 4 asyncs/wave; async r: lane l -> local col w*32+r*8+(l>>3),
    //      phys slot l&7; src chunk = (l&7) ^ l3 ^ ((w&1)*4) ^ r  [x8(col) derived,
    //      bit-disjoint: w*4 mod 8 = (w&1)*4 (bit2), r (bits0-1), no carries]
    const int l3  = lane >> 3;
    const int wsl = lane & 7;
    const int w4  = (w & 1) * 4;

    // ---- fragment reads: phys = (g*4+hi) ^ xc ^ (i*2 | j*2) ^ (w4 for W) ----
    const int l15 = lane & 15;
    const int hi  = lane >> 4;
    const int xc  = (l15 & 7) ^ (l15 >> 3);

    float run_best[4][4];
    int   run_col[4][4];
#pragma unroll
    for (int i = 0; i < 4; ++i)
#pragma unroll
        for (int r = 0; r < 4; ++r) { run_best[i][r] = -3.4e38f; run_col[i][r] = 0; }

    // ---- prologue: stage tile 0 into buf 0; prefetch A regs for tile 1 ----
    {
        float4 f0 = *(const float4*)(Abase + 0);
        float4 f1 = *(const float4*)(Abase + 4);
        half8 hv;
        hv[0] = (_Float16)f0.x; hv[1] = (_Float16)f0.y; hv[2] = (_Float16)f0.z; hv[3] = (_Float16)f0.w;
        hv[4] = (_Float16)f1.x; hv[5] = (_Float16)f1.y; hv[6] = (_Float16)f1.z; hv[7] = (_Float16)f1.w;
        *(half8*)&sA[0][sAw] = hv;
    }
#pragma unroll
    for (int r = 0; r < 4; ++r)
        async16h(Wh + (size_t)(w * 32 + r * 8 + l3) * T_BINS + ((wsl ^ l3 ^ w4 ^ r) * 8),
                 &sW[0][(w * 32 + r * 8) * 64]);
    float4 pa0 = *(const float4*)(Abase + 64);
    float4 pa1 = *(const float4*)(Abase + 68);
    __syncthreads();

    // ---- main loop: 64 tiles (4 bx x 16 k-steps of BK=64), double-buffered ----
    int n = 0;
    for (int bx = 0; bx < 4; ++bx) {
        const int colbase = bx * 256 + w * 32 + l15;
        float bj[2];
        bj[0] = bias[colbase];
        bj[1] = bias[colbase + 16];

        floatx4 acc[4][2];
#pragma unroll
        for (int i = 0; i < 4; ++i)
#pragma unroll
            for (int j = 0; j < 2; ++j) acc[i][j] = (floatx4){0.f, 0.f, 0.f, 0.f};

        for (int t = 0; t < 16; ++t, ++n) {
            const int cur = n & 1;
            const int nxt = cur ^ 1;

            if (n < 63) {   // last slot: nothing left to stage
                const int m   = n + 1;
                const int bxn = m >> 4;
                const int k0n = (m & 15) * 64;

                // 1. W asyncs for tile n+1 (this wave's own 32-col read region)
#pragma unroll
                for (int r = 0; r < 4; ++r)
                    async16h(Wh + (size_t)(bxn * 256 + w * 32 + r * 8 + l3) * T_BINS
                                + k0n + ((wsl ^ l3 ^ w4 ^ r) * 8),
                             &sW[nxt][(w * 32 + r * 8) * 64]);

                // 2. prefetch A regs for tile n+2 (A depends only on k)
                const int kq = ((n + 2) & 15) * 64;
                float4 qa0 = *(const float4*)(Abase + kq + 0);
                float4 qa1 = *(const float4*)(Abase + kq + 4);

                // 3. stage A(n+1) from regs into the other buffer
                {
                    half8 hv;
                    hv[0] = (_Float16)pa0.x; hv[1] = (_Float16)pa0.y;
                    hv[2] = (_Float16)pa0.z; hv[3] = (_Float16)pa0.w;
                    hv[4] = (_Float16)pa1.x; hv[5] = (_Float16)pa1.y;
                    hv[6] = (_Float16)pa1.z; hv[7] = (_Float16)pa1.w;
                    *(half8*)&sA[nxt][sAw] = hv;
                }
                pa0 = qa0; pa1 = qa1;
            }

            // 4. fragments + MFMA: 2 k-subtiles x (4i x 2j) = 16 MFMA/wave/slot
#pragma unroll
            for (int g = 0; g < 2; ++g) {
                half8 ah[4], whf[2];
#pragma unroll
                for (int i = 0; i < 4; ++i)
                    ah[i] = *(const half8*)&sA[cur][(i * 16 + l15) * 64
                                                    + (((g * 4 + hi) ^ xc ^ (i * 2)) * 8)];
#pragma unroll
                for (int j = 0; j < 2; ++j)
                    whf[j] = *(const half8*)&sW[cur][(w * 32 + j * 16 + l15) * 64
                                                     + (((g * 4 + hi) ^ xc ^ (j * 2) ^ w4) * 8)];
#pragma unroll
                for (int i = 0; i < 4; ++i)
#pragma unroll
                    for (int j = 0; j < 2; ++j)
                        acc[i][j] = __builtin_amdgcn_mfma_f32_16x16x32_f16(ah[i], whf[j], acc[i][j], 0, 0, 0);
            }

            // 5. single barrier per slot (drains asyncs + ds_writes, guards swap)
            __syncthreads();
        }

        // fold this bx's acc into the running argmax (cols strictly increase)
#pragma unroll
        for (int i = 0; i < 4; ++i)
#pragma unroll
            for (int r = 0; r < 4; ++r)
#pragma unroll
                for (int j = 0; j < 2; ++j) {
                    float v = acc[i][j][r] + bj[j];
                    if (v > run_best[i][r]) { run_best[i][r] = v; run_col[i][r] = colbase + j * 16; }
                }
    }

    // ---- epilogue: cand (8 waves x 64 rows, 4KB) + trunc_s overlaid on dead sA ----
    unsigned long long (*cand)[64] = reinterpret_cast<unsigned long long (*)[64]>(&sA[0][0]);
    float* trunc_s = reinterpret_cast<float*>(&sA[0][0]) + 1024;   // byte 4096

    // 16-lane (column-lane) reduce; lanes {0,16,32,48} publish per-row candidates
#pragma unroll
    for (int i = 0; i < 4; ++i)
#pragma unroll
        for (int r = 0; r < 4; ++r) {
            float best = run_best[i][r];
            int   bc   = run_col[i][r];
#pragma unroll
            for (int off = 8; off >= 1; off >>= 1) {
                float ov = __shfl_xor(best, off, 64);
                int   oc = __shfl_xor(bc, off, 64);
                if (ov > best || (ov == best && oc < bc)) { best = ov; bc = oc; }
            }
            if (l15 == 0)
                cand[w][i * 16 + hi * 4 + r] = pack_max(best, bc);
        }
    __syncthreads();

    // wave 0: combine 8 col-group candidates per row, write trunc_pos + loss
    if (tid < 64) {
        unsigned long long m01 = cand[0][tid] > cand[1][tid] ? cand[0][tid] : cand[1][tid];
        unsigned long long m23 = cand[2][tid] > cand[3][tid] ? cand[2][tid] : cand[3][tid];
        unsigned long long m45 = cand[4][tid] > cand[5][tid] ? cand[4][tid] : cand[5][tid];
        unsigned long long m67 = cand[6][tid] > cand[7][tid] ? cand[6][tid] : cand[7][tid];
        unsigned long long ma  = m01 > m23 ? m01 : m23;
        unsigned long long mb  = m45 > m67 ? m45 : m67;
        unsigned long long mm  = ma > mb ? ma : mb;
        unsigned col = ~(unsigned)mm;
        float p = (float)col;
        int rowG = by * 64 + tid;
        out_trunc[rowG] = p;
        trunc_s[tid] = p;
        float d = p - labels[rowG];
        float term = d * d * (1.0f / (float)B_ROWS);
#pragma unroll
        for (int off = 32; off >= 1; off >>= 1)
            term += __shfl_down(term, off, 64);
        if (tid == 0) atomicAdd(loss_acc, term);
    }
    __syncthreads();

    // scan phase: wave w handles rows w*8 .. w*8+7; lane covers 16 elements
    for (int rr = 0; rr < 8; ++rr) {
        int row  = w * 8 + rr;
        int rowG = by * 64 + row;
        const float* Hrow = A + (size_t)rowG * T_BINS + lane * 16;
        float4 h0 = *(const float4*)(Hrow + 0);
        float4 h1 = *(const float4*)(Hrow + 4);
        float4 h2 = *(const float4*)(Hrow + 8);
        float4 h3 = *(const float4*)(Hrow + 12);
        float hv[16] = {h0.x, h0.y, h0.z, h0.w, h1.x, h1.y, h1.z, h1.w,
                        h2.x, h2.y, h2.z, h2.w, h3.x, h3.y, h3.z, h3.w};
        float vprod[16];
        float run = 1.f;
#pragma unroll
        for (int j = 0; j < 16; ++j) { run *= (1.f - hv[j]); vprod[j] = run; }
        float x = run;
#pragma unroll
        for (int off = 1; off < 64; off <<= 1) {
            float o = __shfl_up(x, off, 64);
            if (lane >= off) x *= o;
        }
        float pre = __shfl_up(x, 1, 64);
        if (lane == 0) pre = 1.f;

        int p  = (int)trunc_s[row];
        int t0 = lane * 16;
        float sv[16];
#pragma unroll
        for (int j = 0; j < 16; ++j) {
            float s = pre * vprod[j];
            int t = t0 + j;
            if (t >= p) s *= __expf((float)(p - t));
            sv[j] = s;
        }
        float* Srow = out_S + (size_t)rowG * T_BINS + lane * 16;
        *(float4*)(Srow + 0)  = (float4){sv[0],  sv[1],  sv[2],  sv[3]};
        *(float4*)(Srow + 4)  = (float4){sv[4],  sv[5],  sv[6],  sv[7]};
        *(float4*)(Srow + 8)  = (float4){sv[8],  sv[9],  sv[10], sv[11]};
        *(float4*)(Srow + 12) = (float4){sv[12], sv[13], sv[14], sv[15]};
    }
}

// ---------------- fp32 fallback path (round-1 kernels), used if ws too small ----------------
#define BMf 64
#define BKf 16
#define LDSS (BMf + 4)
__global__ __launch_bounds__(256) void gemm_argmax_fp32(
    const float* __restrict__ A, const float* __restrict__ W,
    const float* __restrict__ bias, unsigned long long* __restrict__ rec)
{
    __shared__ float As[BKf][LDSS];
    __shared__ float Ws[BKf][LDSS];
    const int tid = threadIdx.x;
    const int tx = tid & 15, ty = tid >> 4;
    const int bx = blockIdx.x, by = blockIdx.y;
    const int ar = tid >> 2, ak = (tid & 3) << 2;
    const float* Arow = A + (size_t)(by * BMf + ar) * T_BINS + ak;
    const float* Wrow = W + (size_t)(bx * BMf + ar) * T_BINS + ak;
    float acc[4][4];
#pragma unroll
    for (int i = 0; i < 4; ++i)
#pragma unroll
        for (int j = 0; j < 4; ++j) acc[i][j] = 0.f;
    for (int k0 = 0; k0 < T_BINS; k0 += BKf) {
        float4 av = *(const float4*)(Arow + k0);
        float4 wvv = *(const float4*)(Wrow + k0);
        As[ak + 0][ar] = av.x; As[ak + 1][ar] = av.y; As[ak + 2][ar] = av.z; As[ak + 3][ar] = av.w;
        Ws[ak + 0][ar] = wvv.x; Ws[ak + 1][ar] = wvv.y; Ws[ak + 2][ar] = wvv.z; Ws[ak + 3][ar] = wvv.w;
        __syncthreads();
#pragma unroll
        for (int k = 0; k < BKf; ++k) {
            float4 a4 = *(const float4*)&As[k][ty * 4];
            float4 w4 = *(const float4*)&Ws[k][tx * 4];
            float aa[4] = {a4.x, a4.y, a4.z, a4.w};
            float ww[4] = {w4.x, w4.y, w4.z, w4.w};
#pragma unroll
            for (int i = 0; i < 4; ++i)
#pragma unroll
                for (int j = 0; j < 4; ++j) acc[i][j] = fmaf(aa[i], ww[j], acc[i][j]);
        }
        __syncthreads();
    }
    const int colBase = bx * BMf + tx * 4;
    float bv[4];
#pragma unroll
    for (int j = 0; j < 4; ++j) bv[j] = bias[colBase + j];
#pragma unroll
    for (int i = 0; i < 4; ++i) {
        float best = acc[i][0] + bv[0];
        int bc = colBase;
#pragma unroll
        for (int j = 1; j < 4; ++j) {
            float v = acc[i][j] + bv[j];
            if (v > best) { best = v; bc = colBase + j; }
        }
#pragma unroll
        for (int off = 8; off >= 1; off >>= 1) {
            float ov = __shfl_xor(best, off, 64);
            int oc = __shfl_xor(bc, off, 64);
            if (ov > best || (ov == best && oc < bc)) { best = ov; bc = oc; }
        }
        if (tx == 0) atomicMax(&rec[by * BMf + ty * 4 + i], pack_max(best, bc));
    }
}

__global__ __launch_bounds__(256) void finalize_kernel(
    const unsigned long long* __restrict__ rec, const float* __restrict__ labels,
    float* __restrict__ out_trunc, float* __restrict__ loss_acc)
{
    int i = blockIdx.x * 256 + threadIdx.x;
    unsigned col = ~(unsigned)(rec[i] & 0xFFFFFFFFull);
    float p = (float)col;
    out_trunc[i] = p;
    float d = p - labels[i];
    float term = d * d * (1.0f / (float)B_ROWS);
#pragma unroll
    for (int off = 32; off >= 1; off >>= 1)
        term += __shfl_down(term, off, 64);
    __shared__ float partials[4];
    int lane = threadIdx.x & 63, wv = threadIdx.x >> 6;
    if (lane == 0) partials[wv] = term;
    __syncthreads();
    if (threadIdx.x == 0)
        atomicAdd(loss_acc, partials[0] + partials[1] + partials[2] + partials[3]);
}

__global__ __launch_bounds__(256) void scan_kernel_f32(
    const float* __restrict__ H, const float* __restrict__ trunc_f,
    float* __restrict__ Sout)
{
    const int row = blockIdx.x;
    const int tid = threadIdx.x;
    const int lane = tid & 63;
    const int wv = tid >> 6;
    const float4 h = *(const float4*)(H + (size_t)row * T_BINS + tid * 4);
    float l0 = 1.f - h.x;
    float l1 = l0 * (1.f - h.y);
    float l2 = l1 * (1.f - h.z);
    float l3 = l2 * (1.f - h.w);
    float x = l3;
#pragma unroll
    for (int off = 1; off < 64; off <<= 1) {
        float o = __shfl_up(x, off, 64);
        if (lane >= off) x *= o;
    }
    float ex = __shfl_up(x, 1, 64);
    if (lane == 0) ex = 1.f;
    __shared__ float wtot[4];
    if (lane == 63) wtot[wv] = x;
    __syncthreads();
    float wpre = 1.f;
#pragma unroll
    for (int w = 0; w < 3; ++w)
        if (w < wv) wpre *= wtot[w];
    float pre = wpre * ex;
    int p = (int)trunc_f[row];
    int t0 = tid * 4;
    float sv[4] = {pre * l0, pre * l1, pre * l2, pre * l3};
#pragma unroll
    for (int j = 0; j < 4; ++j) {
        int t = t0 + j;
        if (t >= p) sv[j] *= __expf((float)(p - t));
    }
    float4 s4 = {sv[0], sv[1], sv[2], sv[3]};
    *(float4*)(Sout + (size_t)row * T_BINS + tid * 4) = s4;
}

extern "C" void kernel_launch(void* const* d_in, const int* in_sizes, int n_in,
                              void* d_out, int out_size, void* d_ws, size_t ws_size,
                              hipStream_t stream)
{
    const float* hazard = (const float*)d_in[0];   // [B, T]
    const float* labels = (const float*)d_in[1];   // [B]
    const float* W      = (const float*)d_in[2];   // [T, T]
    const float* bias   = (const float*)d_in[3];   // [T]

    float* out       = (float*)d_out;
    float* out_trunc = out;                                       // B floats
    float* out_S     = out + B_ROWS;                              // B*T floats
    float* out_loss  = out + B_ROWS + (size_t)B_ROWS * T_BINS;    // 1 float

    hipMemsetAsync(out_loss, 0, sizeof(float), stream);

    const size_t NW = (size_t)T_BINS * T_BINS;
    if (ws_size >= NW * sizeof(_Float16)) {
        // R12: 8-wave mega (same geometry/bytes as proven R8; TLP 2->4 waves/SIMD)
        _Float16* Wh = (_Float16*)d_ws;
        tof16_kernel<<<(int)(NW / 4 / 256), 256, 0, stream>>>(W, Wh, (int)(NW / 4));
        mega_kernel<<<B_ROWS / 64, 512, 0, stream>>>(
            hazard, Wh, bias, labels, out_trunc, out_S, out_loss);
    } else {
        unsigned long long* rec = (unsigned long long*)out_S;
        hipMemsetAsync(rec, 0, (size_t)B_ROWS * sizeof(unsigned long long), stream);
        dim3 ggrid(T_BINS / BMf, B_ROWS / BMf);
        gemm_argmax_fp32<<<ggrid, 256, 0, stream>>>(hazard, W, bias, rec);
        finalize_kernel<<<B_ROWS / 256, 256, 0, stream>>>(rec, labels, out_trunc, out_loss);
        scan_kernel_f32<<<B_ROWS, 256, 0, stream>>>(hazard, out_trunc, out_S);
    }
}